// Round 3
// baseline (349.833 us; speedup 1.0000x reference)
//
#include <hip/hip_runtime.h>

// ---------------------------------------------------------------------------
// GCN 2-layer, CSR-gather. R14 (R12 minus nontemporal builtins; R12/R13 both
// died in container infra — removing the only new instruction forms vs the
// known-good R11 to rule out a kernel-triggered wedge):
//  - k_agg64 -> k_agg64s: h1 feature-sliced into 4 x [n][16] bf16 slices
//    (3.2MB each); slice pinned to XCD pair via blockIdx%8 so the random
//    gather becomes per-XCD-L2-resident (R11: FETCH 91MB vs 26MB compulsory
//    = L2 capacity misses on 12.8MB h; gather was fabric-bound at 20% HBM).
//  - k_gemm1 writes sliced layout with packed 8B stores.
// ---------------------------------------------------------------------------

#define BSHIFT 7
#define BNODES 128
#define NBUK_MAX 1024
#define CSTR 16
#define CAP 3072
#define CHUNK 4096
#define EPB 16

typedef unsigned short ushort_t;
typedef unsigned int uint_t;
typedef unsigned short us4 __attribute__((ext_vector_type(4)));

__device__ inline ushort_t f2bf(float f) {   // round-to-nearest-even
    uint_t u = __float_as_uint(f);
    return (ushort_t)((u + 0x7FFF + ((u >> 16) & 1)) >> 16);
}
__device__ inline float bf2f(ushort_t b) {
    return __uint_as_float(((uint_t)b) << 16);
}

// init strided cursors to their segment bases
__global__ __launch_bounds__(1024) void k_binit(int* __restrict__ bcur, int nbuk) {
    int t = threadIdx.x;
    if (t < nbuk) bcur[t * CSTR] = t * CAP;
}

// Pass 1: block-aggregated bucket append (R10).
__global__ __launch_bounds__(256) void k_p1(const int* __restrict__ src,
                                            const int* __restrict__ dst,
                                            const float* __restrict__ ew,
                                            int* __restrict__ bcur,
                                            int2* __restrict__ tmp, int E, int nbuk) {
    __shared__ int lcnt[NBUK_MAX];
    __shared__ int lbase[NBUK_MAX];
    const int t = threadIdx.x;
    const int base = blockIdx.x * CHUNK;
    for (int j = t; j < nbuk; j += 256) lcnt[j] = 0;
    __syncthreads();
    int d_r[EPB];
#pragma unroll
    for (int k = 0; k < EPB; ++k) {
        int e = base + k * 256 + t;
        int d = (e < E) ? dst[e] : -1;
        d_r[k] = d;
        if (d >= 0) atomicAdd(&lcnt[d >> BSHIFT], 1);
    }
    __syncthreads();
    for (int j = t; j < nbuk; j += 256) {
        int c = lcnt[j];
        lbase[j] = c ? atomicAdd(&bcur[j * CSTR], c) : 0;
        lcnt[j] = 0;
    }
    __syncthreads();
#pragma unroll
    for (int k = 0; k < EPB; ++k) {
        int d = d_r[k];
        if (d < 0) continue;
        int e = base + k * 256 + t;
        int b = d >> BSHIFT;
        int p = lbase[b] + atomicAdd(&lcnt[b], 1);
        if (p >= nbuk * CAP) continue;
        int2 pk;
        pk.x = src[e] | ((d & (BNODES - 1)) << 17);
        pk.y = __float_as_int(ew[e]);
        tmp[p] = pk;
    }
}

// Scan final bucket counts -> dense boff[nbuk+1].
__global__ __launch_bounds__(1024) void k_pscan(const int* __restrict__ bcur,
                                                int* __restrict__ boff, int nbuk) {
    __shared__ int lds[1024];
    const int t = threadIdx.x;
    int v = (t < nbuk) ? (bcur[t * CSTR] - t * CAP) : 0;
    lds[t] = v;
    __syncthreads();
    for (int off = 1; off < 1024; off <<= 1) {
        int u = (t >= off) ? lds[t - off] : 0;
        __syncthreads();
        lds[t] += u;
        __syncthreads();
    }
    if (t < nbuk) boff[t] = lds[t] - v;
    if (t == nbuk - 1) boff[nbuk] = lds[t];
}

// Pass 2: per-bucket finalize -> dense CSR epack {src, ew}, rowptr, dinv.
__global__ __launch_bounds__(256) void k_p2(const int2* __restrict__ tmp,
                                            const int* __restrict__ bcur,
                                            const int* __restrict__ boff,
                                            int* __restrict__ rowptr,
                                            int2* __restrict__ epack,
                                            float* __restrict__ dinv,
                                            int n, int nbuk) {
    __shared__ int cnt[BNODES];
    __shared__ int pos[BNODES];
    __shared__ float degf[BNODES];
    const int b = blockIdx.x, t = threadIdx.x;
    const int node0 = b << BSHIFT;
    if (t < BNODES) { cnt[t] = 0; degf[t] = 0.f; }
    __syncthreads();
    const int lo_t = b * CAP, hi_t = bcur[b * CSTR];
    const int outb = boff[b];
    for (int i = lo_t + t; i < hi_t; i += 256) {
        int2 pk = tmp[i];
        int dlo = (pk.x >> 17) & (BNODES - 1);
        atomicAdd(&cnt[dlo], 1);
        atomicAdd(&degf[dlo], __int_as_float(pk.y));
    }
    __syncthreads();
    int own = (t < BNODES) ? cnt[t] : 0;
    if (t < BNODES) pos[t] = own;
    __syncthreads();
    for (int off = 1; off < BNODES; off <<= 1) {
        int u = (t < BNODES && t >= off) ? pos[t - off] : 0;
        __syncthreads();
        if (t < BNODES) pos[t] += u;
        __syncthreads();
    }
    if (t < BNODES) {
        int excl = pos[t] - own;
        int node = node0 + t;
        if (node < n) {
            rowptr[node] = outb + excl;
            dinv[node] = rsqrtf(1.0f + degf[t]);
        }
        pos[t] = excl;
    }
    if (b == nbuk - 1 && t == 0) rowptr[n] = outb + (hi_t - lo_t);
    __syncthreads();
    for (int i = lo_t + t; i < hi_t; i += 256) {
        int2 pk = tmp[i];
        int dlo = (pk.x >> 17) & (BNODES - 1);
        int p = outb + atomicAdd(&pos[dlo], 1);
        int2 o;
        o.x = pk.x & 0x1FFFF;
        o.y = pk.y;
        epack[p] = o;
    }
}

// h (sliced bf16): h[s][node][16] with global feature f = s*16 + j.
// h[s][node][j] = (x[node][:] @ W[:][s*16+j]) * dinv[node]
// thread = (node ng, feature-quad fg): per k 1 ds_read_b128 + 1 broadcast + 4 FMA.
__global__ __launch_bounds__(256) void k_gemm1(const float* __restrict__ x,
                                               const float* __restrict__ W,
                                               const float* __restrict__ dinv,
                                               ushort_t* __restrict__ h, int n) {
    __shared__ float Ws[128 * 64];   // 32 KB
    __shared__ float xs[16][128];    // 8 KB
    const int t = threadIdx.x;
    for (int i = t; i < 128 * 64; i += 256) Ws[i] = W[i];
    const int node0 = blockIdx.x * 16;
    for (int i = t; i < 16 * 128; i += 256) {
        int nn = i >> 7, kk = i & 127;
        int node = node0 + nn;
        xs[nn][kk] = (node < n) ? x[(size_t)node * 128 + kk] : 0.0f;
    }
    __syncthreads();
    const int fg = t & 15;   // feature quad: f = 4*fg .. 4*fg+3
    const int ng = t >> 4;   // node within block: 0..15
    const float4* Ws4 = (const float4*)Ws;  // Ws4[k*16 + fg]
    float4 acc = {0.f, 0.f, 0.f, 0.f};
#pragma unroll 8
    for (int k = 0; k < 128; ++k) {
        float4 w = Ws4[k * 16 + fg];
        float xv = xs[ng][k];
        acc.x = fmaf(xv, w.x, acc.x);
        acc.y = fmaf(xv, w.y, acc.y);
        acc.z = fmaf(xv, w.z, acc.z);
        acc.w = fmaf(xv, w.w, acc.w);
    }
    const int node = node0 + ng;
    if (node < n) {
        float di = dinv[node];
        const int slice = fg >> 2;
        size_t base = (size_t)slice * ((size_t)n * 16) + (size_t)node * 16 + (size_t)(fg & 3) * 4;
        us4 pk;
        pk.x = f2bf(acc.x * di);
        pk.y = f2bf(acc.y * di);
        pk.z = f2bf(acc.z * di);
        pk.w = f2bf(acc.w * di);
        *(us4*)(h + base) = pk;   // one 8B store
    }
}

// Gather-aggregate, F=64, feature-sliced h: slice = (blockIdx%8)&3 so each
// XCD pair works one 3.2MB slice -> gather is L2-resident.
// 16-lane group per node (lane = feature-in-slice), 8 rows in flight.
// agg[node][s*16+lane] = di * (sum_e h[s][src][lane]*ew + h[s][node][lane])
__global__ __launch_bounds__(256) void k_agg64s(const ushort_t* __restrict__ h,
                                                const int* __restrict__ rowptr,
                                                const int2* __restrict__ ep,
                                                const float* __restrict__ dinv,
                                                float* __restrict__ agg, int n) {
    const int bid = blockIdx.x;
    const int xcd = bid & 7;            // blockIdx%8 -> XCD (round-robin dispatch)
    const int slice = xcd & 3;          // slice s lives on XCDs {s, s+4}
    const int g = ((bid >> 3) << 1) + (xcd >> 2);   // node group, interleaved per pair
    if (g * 16 >= n) return;
    const int t = threadIdx.x;
    const int sub = t >> 4;             // node within group: 0..15
    const int lane = t & 15;            // feature within slice
    const int node = g * 16 + sub;
    if (node >= n) return;
    const ushort_t* __restrict__ hs = h + (size_t)slice * ((size_t)n * 16);
    const float di = dinv[node];
    const int lo = rowptr[node], hi = rowptr[node + 1];
    float accE = 0.f;
    int i = lo;
    for (; i + 7 < hi; i += 8) {
        int2 p0 = ep[i], p1 = ep[i + 1], p2 = ep[i + 2], p3 = ep[i + 3];
        int2 p4 = ep[i + 4], p5 = ep[i + 5], p6 = ep[i + 6], p7 = ep[i + 7];
        float v0 = bf2f(hs[(size_t)p0.x * 16 + lane]);
        float v1 = bf2f(hs[(size_t)p1.x * 16 + lane]);
        float v2 = bf2f(hs[(size_t)p2.x * 16 + lane]);
        float v3 = bf2f(hs[(size_t)p3.x * 16 + lane]);
        float v4 = bf2f(hs[(size_t)p4.x * 16 + lane]);
        float v5 = bf2f(hs[(size_t)p5.x * 16 + lane]);
        float v6 = bf2f(hs[(size_t)p6.x * 16 + lane]);
        float v7 = bf2f(hs[(size_t)p7.x * 16 + lane]);
        accE = fmaf(v0, __int_as_float(p0.y), accE);
        accE = fmaf(v1, __int_as_float(p1.y), accE);
        accE = fmaf(v2, __int_as_float(p2.y), accE);
        accE = fmaf(v3, __int_as_float(p3.y), accE);
        accE = fmaf(v4, __int_as_float(p4.y), accE);
        accE = fmaf(v5, __int_as_float(p5.y), accE);
        accE = fmaf(v6, __int_as_float(p6.y), accE);
        accE = fmaf(v7, __int_as_float(p7.y), accE);
    }
    for (; i < hi; ++i) {
        int2 p = ep[i];
        accE = fmaf(bf2f(hs[(size_t)p.x * 16 + lane]), __int_as_float(p.y), accE);
    }
    float self = bf2f(hs[(size_t)node * 16 + lane]);
    agg[(size_t)node * 64 + (size_t)slice * 16 + lane] = di * (accE + self);
}

// Gather-aggregate, F=16, bf16 h: 16-lane group per node, 4 rows in flight.
__global__ __launch_bounds__(256) void k_agg16(const ushort_t* __restrict__ h,
                                               const int* __restrict__ rowptr,
                                               const int2* __restrict__ ep,
                                               const float* __restrict__ dinv,
                                               float* __restrict__ agg, int n) {
    const int node = (blockIdx.x * 256 + threadIdx.x) >> 4;
    const int lane = threadIdx.x & 15;
    if (node >= n) return;
    const float di = dinv[node];
    float accE = 0.f;
    const int lo = rowptr[node], hi = rowptr[node + 1];
    int i = lo;
    for (; i + 3 < hi; i += 4) {
        int2 p0 = ep[i], p1 = ep[i + 1], p2 = ep[i + 2], p3 = ep[i + 3];
        float v0 = bf2f(h[(size_t)p0.x * 16 + lane]);
        float v1 = bf2f(h[(size_t)p1.x * 16 + lane]);
        float v2 = bf2f(h[(size_t)p2.x * 16 + lane]);
        float v3 = bf2f(h[(size_t)p3.x * 16 + lane]);
        accE = fmaf(v0, __int_as_float(p0.y), accE);
        accE = fmaf(v1, __int_as_float(p1.y), accE);
        accE = fmaf(v2, __int_as_float(p2.y), accE);
        accE = fmaf(v3, __int_as_float(p3.y), accE);
    }
    for (; i < hi; ++i) {
        int2 p = ep[i];
        accE = fmaf(bf2f(h[(size_t)p.x * 16 + lane]), __int_as_float(p.y), accE);
    }
    float self = bf2f(h[(size_t)node * 16 + lane]);
    agg[(size_t)node * 16 + lane] = di * (accE + self);
}

// h2s[n][16] (bf16) = (relu(a[n][64] + b1) @ W[64][16]) * dinv[node]
__global__ __launch_bounds__(256) void k_gemm2(const float* __restrict__ a,
                                               const float* __restrict__ W,
                                               const float* __restrict__ b1,
                                               const float* __restrict__ dinv,
                                               ushort_t* __restrict__ h2, int n) {
    __shared__ float Ws[64 * 16];
    __shared__ float xs[32][68];
    const int t = threadIdx.x;
    for (int i = t; i < 64 * 16; i += 256) Ws[i] = W[i];
    const int node0 = blockIdx.x * 32;
    for (int i = t; i < 32 * 64; i += 256) {
        int nn = i >> 6, kk = i & 63;
        int node = node0 + nn;
        xs[nn][kk] = (node < n) ? fmaxf(a[(size_t)node * 64 + kk] + b1[kk], 0.0f) : 0.0f;
    }
    __syncthreads();
    const int f = t & 15;
    const int ng = t >> 4;
    float a0 = 0.f, a1 = 0.f;
#pragma unroll 4
    for (int k = 0; k < 64; ++k) {
        float wv = Ws[k * 16 + f];
        a0 = fmaf(xs[ng][k], wv, a0);
        a1 = fmaf(xs[ng + 16][k], wv, a1);
    }
    if (node0 + ng < n)
        h2[(size_t)(node0 + ng) * 16 + f] = f2bf(a0 * dinv[node0 + ng]);
    if (node0 + ng + 16 < n)
        h2[(size_t)(node0 + ng + 16) * 16 + f] = f2bf(a1 * dinv[node0 + ng + 16]);
}

// In-place: out[i][:] = log_softmax(out[i][:] + b2)
__global__ void k_logsoftmax(float* __restrict__ out, const float* __restrict__ b2, int n) {
    int i = blockIdx.x * blockDim.x + threadIdx.x;
    if (i >= n) return;
    const size_t base = (size_t)i * 16;
    float v[16];
#pragma unroll
    for (int f = 0; f < 16; ++f) v[f] = out[base + f] + b2[f];
    float m = v[0];
#pragma unroll
    for (int f = 1; f < 16; ++f) m = fmaxf(m, v[f]);
    float s = 0.f;
#pragma unroll
    for (int f = 0; f < 16; ++f) s += __expf(v[f] - m);
    float lse = __logf(s);
#pragma unroll
    for (int f = 0; f < 16; ++f) out[base + f] = v[f] - m - lse;
}

extern "C" void kernel_launch(void* const* d_in, const int* in_sizes, int n_in,
                              void* d_out, int out_size, void* d_ws, size_t ws_size,
                              hipStream_t stream) {
    const float* x  = (const float*)d_in[0];
    const int*   ei = (const int*)d_in[1];   // [2, E]
    const float* ew = (const float*)d_in[2];
    const float* W1 = (const float*)d_in[3];
    const float* b1 = (const float*)d_in[4];
    const float* W2 = (const float*)d_in[5];
    const float* b2 = (const float*)d_in[6];
    float* out = (float*)d_out;

    const int n = in_sizes[0] / 128;  // 100000
    const int E = in_sizes[2];        // 1600000
    const int* srcv = ei;
    const int* dstv = ei + E;
    const int nbuk = (n + BNODES - 1) >> BSHIFT;  // 782

    // Workspace (4B units). tmp (19.2MB) aliases agg1 (25.6MB, dead until
    // k_agg64s which runs after k_p2 retires tmp).
    float* wsf = (float*)d_ws;
    size_t off = 0;
    float* dinv = wsf + off; off += n;
    ushort_t* h1b = (ushort_t*)(wsf + off); off += (size_t)n * 32;  // bf16: 4 slices x [n][16]; reused bf16[n*16]
    float* agg1 = wsf + off; off += (size_t)n * 64;
    off = (off + 1) & ~(size_t)1;                     // 8B align
    int2* epack = (int2*)(wsf + off); off += (size_t)E * 2;
    int* rowptr = (int*)(wsf + off); off += n + 1;
    int* boff_d = (int*)(wsf + off); off += NBUK_MAX + 1;
    int* bcur   = (int*)(wsf + off); off += (size_t)NBUK_MAX * CSTR;
    int2* tmp   = (int2*)agg1;                        // [nbuk*CAP]

    const int TB = 256;

    // --- CSR build: cursor init -> block-aggregated append -> scan -> finalize ---
    k_binit<<<1, 1024, 0, stream>>>(bcur, nbuk);
    k_p1<<<(E + CHUNK - 1) / CHUNK, TB, 0, stream>>>(srcv, dstv, ew, bcur, tmp, E, nbuk);
    k_pscan<<<1, 1024, 0, stream>>>(bcur, boff_d, nbuk);
    k_p2<<<nbuk, TB, 0, stream>>>(tmp, bcur, boff_d, rowptr, epack, dinv, n, nbuk);

    // --- layer 1: gemm (dinv-prescaled, sliced bf16 out) + sliced gather-agg ---
    k_gemm1<<<(n + 15) / 16, TB, 0, stream>>>(x, W1, dinv, h1b, n);
    {
        const int gps = (n + 15) / 16;       // node groups per slice
        const int pairs = (gps + 1) / 2;     // groups per XCD-pair member
        k_agg64s<<<pairs * 8, TB, 0, stream>>>(h1b, rowptr, epack, dinv, agg1, n);
    }

    // --- layer 2: gemm (+bias1+relu, prescaled, bf16 out) + gather-agg into d_out ---
    k_gemm2<<<(n + 31) / 32, TB, 0, stream>>>(agg1, W2, b1, dinv, h1b, n);
    k_agg16<<<(n * 16 + TB - 1) / TB, TB, 0, stream>>>(h1b, rowptr, epack, dinv, out, n);

    // --- epilogue ---
    k_logsoftmax<<<(n + TB - 1) / TB, TB, 0, stream>>>(out, b2, n);
}

// Round 4
// 316.939 us; speedup vs baseline: 1.1038x; 1.1038x over previous
//
#include <hip/hip_runtime.h>

// ---------------------------------------------------------------------------
// GCN 2-layer, CSR-gather. R15 (post-mortem of R14 slicing experiment):
//  - R14 result: slicing made h L2-resident (FETCH 91->74MB, exactly the
//    predicted decomposition) but dur 75->97us => gather is LATENCY-bound,
//    not BW/L2-capacity-bound. Slicing reverted (monolithic h[n][64]).
//  - k_agg64: double-buffered ep prefetch (ep batch k+1 issued before batch
//    k's gathers are consumed) to overlap the two dependent round-trips that
//    R11's VGPR=24 build provably serialized; readfirstlane(node) so
//    rowptr/ep addresses are SGPR-provable (s_load path if compiler takes it).
//    Target VGPR ~48-56 (<=64 keeps 8 waves/SIMD).
//  - k_gemm1 keeps packed 8B us4 store, monolithic layout.
// ---------------------------------------------------------------------------

#define BSHIFT 7
#define BNODES 128
#define NBUK_MAX 1024
#define CSTR 16
#define CAP 3072
#define CHUNK 4096
#define EPB 16

typedef unsigned short ushort_t;
typedef unsigned int uint_t;
typedef unsigned short us4 __attribute__((ext_vector_type(4)));

__device__ inline ushort_t f2bf(float f) {   // round-to-nearest-even
    uint_t u = __float_as_uint(f);
    return (ushort_t)((u + 0x7FFF + ((u >> 16) & 1)) >> 16);
}
__device__ inline float bf2f(ushort_t b) {
    return __uint_as_float(((uint_t)b) << 16);
}

// init strided cursors to their segment bases
__global__ __launch_bounds__(1024) void k_binit(int* __restrict__ bcur, int nbuk) {
    int t = threadIdx.x;
    if (t < nbuk) bcur[t * CSTR] = t * CAP;
}

// Pass 1: block-aggregated bucket append (R10).
__global__ __launch_bounds__(256) void k_p1(const int* __restrict__ src,
                                            const int* __restrict__ dst,
                                            const float* __restrict__ ew,
                                            int* __restrict__ bcur,
                                            int2* __restrict__ tmp, int E, int nbuk) {
    __shared__ int lcnt[NBUK_MAX];
    __shared__ int lbase[NBUK_MAX];
    const int t = threadIdx.x;
    const int base = blockIdx.x * CHUNK;
    for (int j = t; j < nbuk; j += 256) lcnt[j] = 0;
    __syncthreads();
    int d_r[EPB];
#pragma unroll
    for (int k = 0; k < EPB; ++k) {
        int e = base + k * 256 + t;
        int d = (e < E) ? dst[e] : -1;
        d_r[k] = d;
        if (d >= 0) atomicAdd(&lcnt[d >> BSHIFT], 1);
    }
    __syncthreads();
    for (int j = t; j < nbuk; j += 256) {
        int c = lcnt[j];
        lbase[j] = c ? atomicAdd(&bcur[j * CSTR], c) : 0;
        lcnt[j] = 0;
    }
    __syncthreads();
#pragma unroll
    for (int k = 0; k < EPB; ++k) {
        int d = d_r[k];
        if (d < 0) continue;
        int e = base + k * 256 + t;
        int b = d >> BSHIFT;
        int p = lbase[b] + atomicAdd(&lcnt[b], 1);
        if (p >= nbuk * CAP) continue;
        int2 pk;
        pk.x = src[e] | ((d & (BNODES - 1)) << 17);
        pk.y = __float_as_int(ew[e]);
        tmp[p] = pk;
    }
}

// Scan final bucket counts -> dense boff[nbuk+1].
__global__ __launch_bounds__(1024) void k_pscan(const int* __restrict__ bcur,
                                                int* __restrict__ boff, int nbuk) {
    __shared__ int lds[1024];
    const int t = threadIdx.x;
    int v = (t < nbuk) ? (bcur[t * CSTR] - t * CAP) : 0;
    lds[t] = v;
    __syncthreads();
    for (int off = 1; off < 1024; off <<= 1) {
        int u = (t >= off) ? lds[t - off] : 0;
        __syncthreads();
        lds[t] += u;
        __syncthreads();
    }
    if (t < nbuk) boff[t] = lds[t] - v;
    if (t == nbuk - 1) boff[nbuk] = lds[t];
}

// Pass 2: per-bucket finalize -> dense CSR epack {src, ew}, rowptr, dinv.
__global__ __launch_bounds__(256) void k_p2(const int2* __restrict__ tmp,
                                            const int* __restrict__ bcur,
                                            const int* __restrict__ boff,
                                            int* __restrict__ rowptr,
                                            int2* __restrict__ epack,
                                            float* __restrict__ dinv,
                                            int n, int nbuk) {
    __shared__ int cnt[BNODES];
    __shared__ int pos[BNODES];
    __shared__ float degf[BNODES];
    const int b = blockIdx.x, t = threadIdx.x;
    const int node0 = b << BSHIFT;
    if (t < BNODES) { cnt[t] = 0; degf[t] = 0.f; }
    __syncthreads();
    const int lo_t = b * CAP, hi_t = bcur[b * CSTR];
    const int outb = boff[b];
    for (int i = lo_t + t; i < hi_t; i += 256) {
        int2 pk = tmp[i];
        int dlo = (pk.x >> 17) & (BNODES - 1);
        atomicAdd(&cnt[dlo], 1);
        atomicAdd(&degf[dlo], __int_as_float(pk.y));
    }
    __syncthreads();
    int own = (t < BNODES) ? cnt[t] : 0;
    if (t < BNODES) pos[t] = own;
    __syncthreads();
    for (int off = 1; off < BNODES; off <<= 1) {
        int u = (t < BNODES && t >= off) ? pos[t - off] : 0;
        __syncthreads();
        if (t < BNODES) pos[t] += u;
        __syncthreads();
    }
    if (t < BNODES) {
        int excl = pos[t] - own;
        int node = node0 + t;
        if (node < n) {
            rowptr[node] = outb + excl;
            dinv[node] = rsqrtf(1.0f + degf[t]);
        }
        pos[t] = excl;
    }
    if (b == nbuk - 1 && t == 0) rowptr[n] = outb + (hi_t - lo_t);
    __syncthreads();
    for (int i = lo_t + t; i < hi_t; i += 256) {
        int2 pk = tmp[i];
        int dlo = (pk.x >> 17) & (BNODES - 1);
        int p = outb + atomicAdd(&pos[dlo], 1);
        int2 o;
        o.x = pk.x & 0x1FFFF;
        o.y = pk.y;
        epack[p] = o;
    }
}

// h1s[n][64] (bf16) = (x[n][128] @ W[128][64]) * dinv[node]
// thread = (node ng, feature-quad fg): per k 1 ds_read_b128 + 1 broadcast + 4 FMA.
__global__ __launch_bounds__(256) void k_gemm1(const float* __restrict__ x,
                                               const float* __restrict__ W,
                                               const float* __restrict__ dinv,
                                               ushort_t* __restrict__ h, int n) {
    __shared__ float Ws[128 * 64];   // 32 KB
    __shared__ float xs[16][128];    // 8 KB
    const int t = threadIdx.x;
    for (int i = t; i < 128 * 64; i += 256) Ws[i] = W[i];
    const int node0 = blockIdx.x * 16;
    for (int i = t; i < 16 * 128; i += 256) {
        int nn = i >> 7, kk = i & 127;
        int node = node0 + nn;
        xs[nn][kk] = (node < n) ? x[(size_t)node * 128 + kk] : 0.0f;
    }
    __syncthreads();
    const int fg = t & 15;   // feature quad: f = 4*fg .. 4*fg+3
    const int ng = t >> 4;   // node within block: 0..15
    const float4* Ws4 = (const float4*)Ws;  // Ws4[k*16 + fg]
    float4 acc = {0.f, 0.f, 0.f, 0.f};
#pragma unroll 8
    for (int k = 0; k < 128; ++k) {
        float4 w = Ws4[k * 16 + fg];
        float xv = xs[ng][k];
        acc.x = fmaf(xv, w.x, acc.x);
        acc.y = fmaf(xv, w.y, acc.y);
        acc.z = fmaf(xv, w.z, acc.z);
        acc.w = fmaf(xv, w.w, acc.w);
    }
    const int node = node0 + ng;
    if (node < n) {
        float di = dinv[node];
        us4 pk;
        pk.x = f2bf(acc.x * di);
        pk.y = f2bf(acc.y * di);
        pk.z = f2bf(acc.z * di);
        pk.w = f2bf(acc.w * di);
        *(us4*)(h + (size_t)node * 64 + fg * 4) = pk;   // one 8B store
    }
}

// Gather-aggregate, F=64, bf16 h: one wave per node, lane = feature.
// Double-buffered ep prefetch: batch k+1's ep loads are issued before batch
// k's gathers are consumed, hiding the ep round-trip under the h round-trip.
// node is readfirstlane'd so rowptr/ep addressing is SGPR-provable.
__global__ __launch_bounds__(256) void k_agg64(const ushort_t* __restrict__ h,
                                               const int* __restrict__ rowptr,
                                               const int2* __restrict__ ep,
                                               const float* __restrict__ dinv,
                                               float* __restrict__ agg, int n) {
    const int node = __builtin_amdgcn_readfirstlane((int)((blockIdx.x * 256 + threadIdx.x) >> 6));
    const int lane = threadIdx.x & 63;
    if (node >= n) return;
    const float di = dinv[node];
    const int lo = rowptr[node], hi = rowptr[node + 1];
    const ushort_t* __restrict__ hl = h + lane;
    float accE = 0.f;
    int i = lo;
    if (i + 8 <= hi) {
        int2 pb[8], nb[8];
#pragma unroll
        for (int k = 0; k < 8; ++k) pb[k] = ep[i + k];
        i += 8;
        for (; i + 8 <= hi; i += 8) {
            // issue next batch's ep loads first (independent of pb)
#pragma unroll
            for (int k = 0; k < 8; ++k) nb[k] = ep[i + k];
            float v[8];
#pragma unroll
            for (int k = 0; k < 8; ++k) v[k] = bf2f(hl[(size_t)pb[k].x * 64]);
#pragma unroll
            for (int k = 0; k < 8; ++k) accE = fmaf(v[k], __int_as_float(pb[k].y), accE);
#pragma unroll
            for (int k = 0; k < 8; ++k) pb[k] = nb[k];
        }
        {   // drain last full batch
            float v[8];
#pragma unroll
            for (int k = 0; k < 8; ++k) v[k] = bf2f(hl[(size_t)pb[k].x * 64]);
#pragma unroll
            for (int k = 0; k < 8; ++k) accE = fmaf(v[k], __int_as_float(pb[k].y), accE);
        }
    }
    for (; i < hi; ++i) {
        int2 p = ep[i];
        accE = fmaf(bf2f(hl[(size_t)p.x * 64]), __int_as_float(p.y), accE);
    }
    float self = bf2f(hl[(size_t)node * 64]);
    agg[(size_t)node * 64 + lane] = di * (accE + self);
}

// Gather-aggregate, F=16, bf16 h: 16-lane group per node, 4 rows in flight.
__global__ __launch_bounds__(256) void k_agg16(const ushort_t* __restrict__ h,
                                               const int* __restrict__ rowptr,
                                               const int2* __restrict__ ep,
                                               const float* __restrict__ dinv,
                                               float* __restrict__ agg, int n) {
    const int node = (blockIdx.x * 256 + threadIdx.x) >> 4;
    const int lane = threadIdx.x & 15;
    if (node >= n) return;
    const float di = dinv[node];
    float accE = 0.f;
    const int lo = rowptr[node], hi = rowptr[node + 1];
    int i = lo;
    for (; i + 3 < hi; i += 4) {
        int2 p0 = ep[i], p1 = ep[i + 1], p2 = ep[i + 2], p3 = ep[i + 3];
        float v0 = bf2f(h[(size_t)p0.x * 16 + lane]);
        float v1 = bf2f(h[(size_t)p1.x * 16 + lane]);
        float v2 = bf2f(h[(size_t)p2.x * 16 + lane]);
        float v3 = bf2f(h[(size_t)p3.x * 16 + lane]);
        accE = fmaf(v0, __int_as_float(p0.y), accE);
        accE = fmaf(v1, __int_as_float(p1.y), accE);
        accE = fmaf(v2, __int_as_float(p2.y), accE);
        accE = fmaf(v3, __int_as_float(p3.y), accE);
    }
    for (; i < hi; ++i) {
        int2 p = ep[i];
        accE = fmaf(bf2f(h[(size_t)p.x * 16 + lane]), __int_as_float(p.y), accE);
    }
    float self = bf2f(h[(size_t)node * 16 + lane]);
    agg[(size_t)node * 16 + lane] = di * (accE + self);
}

// h2s[n][16] (bf16) = (relu(a[n][64] + b1) @ W[64][16]) * dinv[node]
__global__ __launch_bounds__(256) void k_gemm2(const float* __restrict__ a,
                                               const float* __restrict__ W,
                                               const float* __restrict__ b1,
                                               const float* __restrict__ dinv,
                                               ushort_t* __restrict__ h2, int n) {
    __shared__ float Ws[64 * 16];
    __shared__ float xs[32][68];
    const int t = threadIdx.x;
    for (int i = t; i < 64 * 16; i += 256) Ws[i] = W[i];
    const int node0 = blockIdx.x * 32;
    for (int i = t; i < 32 * 64; i += 256) {
        int nn = i >> 6, kk = i & 63;
        int node = node0 + nn;
        xs[nn][kk] = (node < n) ? fmaxf(a[(size_t)node * 64 + kk] + b1[kk], 0.0f) : 0.0f;
    }
    __syncthreads();
    const int f = t & 15;
    const int ng = t >> 4;
    float a0 = 0.f, a1 = 0.f;
#pragma unroll 4
    for (int k = 0; k < 64; ++k) {
        float wv = Ws[k * 16 + f];
        a0 = fmaf(xs[ng][k], wv, a0);
        a1 = fmaf(xs[ng + 16][k], wv, a1);
    }
    if (node0 + ng < n)
        h2[(size_t)(node0 + ng) * 16 + f] = f2bf(a0 * dinv[node0 + ng]);
    if (node0 + ng + 16 < n)
        h2[(size_t)(node0 + ng + 16) * 16 + f] = f2bf(a1 * dinv[node0 + ng + 16]);
}

// In-place: out[i][:] = log_softmax(out[i][:] + b2)
__global__ void k_logsoftmax(float* __restrict__ out, const float* __restrict__ b2, int n) {
    int i = blockIdx.x * blockDim.x + threadIdx.x;
    if (i >= n) return;
    const size_t base = (size_t)i * 16;
    float v[16];
#pragma unroll
    for (int f = 0; f < 16; ++f) v[f] = out[base + f] + b2[f];
    float m = v[0];
#pragma unroll
    for (int f = 1; f < 16; ++f) m = fmaxf(m, v[f]);
    float s = 0.f;
#pragma unroll
    for (int f = 0; f < 16; ++f) s += __expf(v[f] - m);
    float lse = __logf(s);
#pragma unroll
    for (int f = 0; f < 16; ++f) out[base + f] = v[f] - m - lse;
}

extern "C" void kernel_launch(void* const* d_in, const int* in_sizes, int n_in,
                              void* d_out, int out_size, void* d_ws, size_t ws_size,
                              hipStream_t stream) {
    const float* x  = (const float*)d_in[0];
    const int*   ei = (const int*)d_in[1];   // [2, E]
    const float* ew = (const float*)d_in[2];
    const float* W1 = (const float*)d_in[3];
    const float* b1 = (const float*)d_in[4];
    const float* W2 = (const float*)d_in[5];
    const float* b2 = (const float*)d_in[6];
    float* out = (float*)d_out;

    const int n = in_sizes[0] / 128;  // 100000
    const int E = in_sizes[2];        // 1600000
    const int* srcv = ei;
    const int* dstv = ei + E;
    const int nbuk = (n + BNODES - 1) >> BSHIFT;  // 782

    // Workspace (4B units). tmp (19.2MB) aliases agg1 (25.6MB, dead until
    // k_agg64 which runs after k_p2 retires tmp).
    float* wsf = (float*)d_ws;
    size_t off = 0;
    float* dinv = wsf + off; off += n;
    ushort_t* h1b = (ushort_t*)(wsf + off); off += (size_t)n * 32;  // bf16[n*64]; reused bf16[n*16]
    float* agg1 = wsf + off; off += (size_t)n * 64;
    off = (off + 1) & ~(size_t)1;                     // 8B align
    int2* epack = (int2*)(wsf + off); off += (size_t)E * 2;
    int* rowptr = (int*)(wsf + off); off += n + 1;
    int* boff_d = (int*)(wsf + off); off += NBUK_MAX + 1;
    int* bcur   = (int*)(wsf + off); off += (size_t)NBUK_MAX * CSTR;
    int2* tmp   = (int2*)agg1;                        // [nbuk*CAP]

    const int TB = 256;

    // --- CSR build: cursor init -> block-aggregated append -> scan -> finalize ---
    k_binit<<<1, 1024, 0, stream>>>(bcur, nbuk);
    k_p1<<<(E + CHUNK - 1) / CHUNK, TB, 0, stream>>>(srcv, dstv, ew, bcur, tmp, E, nbuk);
    k_pscan<<<1, 1024, 0, stream>>>(bcur, boff_d, nbuk);
    k_p2<<<nbuk, TB, 0, stream>>>(tmp, bcur, boff_d, rowptr, epack, dinv, n, nbuk);

    // --- layer 1: gemm (dinv-prescaled, bf16 out) + gather-agg ---
    k_gemm1<<<(n + 15) / 16, TB, 0, stream>>>(x, W1, dinv, h1b, n);
    k_agg64<<<(n * 64 + TB - 1) / TB, TB, 0, stream>>>(h1b, rowptr, epack, dinv, agg1, n);

    // --- layer 2: gemm (+bias1+relu, prescaled, bf16 out) + gather-agg into d_out ---
    k_gemm2<<<(n + 31) / 32, TB, 0, stream>>>(agg1, W2, b1, dinv, h1b, n);
    k_agg16<<<(n * 16 + TB - 1) / TB, TB, 0, stream>>>(h1b, rowptr, epack, dinv, out, n);

    // --- epilogue ---
    k_logsoftmax<<<(n + TB - 1) / TB, TB, 0, stream>>>(out, b2, n);
}

// Round 5
// 299.664 us; speedup vs baseline: 1.1674x; 1.0576x over previous
//
#include <hip/hip_runtime.h>

// ---------------------------------------------------------------------------
// GCN 2-layer, CSR-gather. R16 (on R15, total 316.9us):
//  - R15 confirmed: agg64 off the critical top (<66us). New #1: k_gemm1 66us
//    with SQ_LDS_BANK_CONFLICT = 3.2M = waves(25k) x k(128) -> every xs
//    broadcast read was a 4-way bank conflict (node stride 512B = 0 mod 32
//    banks), and 1 b128 + 1 b32 per 4 FMA is LDS-issue bound (~4.5 cyc/FMA).
//  - k_gemm1 v2: 64-node block, 4x4 register tile (nodes ng+16j x feats
//    4fg..4fg+3), K processed in two 64-wide halves staged in xs[64][68]
//    (pad 68 => node stride = 4 banks; ng-stride-16 node map => wave's 4 row
//    addrs hit 4 distinct bank quads -> conflict-free). Per 4k: 8 ds_read_b128
//    for 64 FMA (~1.0 LDS-cyc/FMA). Same k-accumulation order -> bit-identical.
// ---------------------------------------------------------------------------

#define BSHIFT 7
#define BNODES 128
#define NBUK_MAX 1024
#define CSTR 16
#define CAP 3072
#define CHUNK 4096
#define EPB 16

typedef unsigned short ushort_t;
typedef unsigned int uint_t;
typedef unsigned short us4 __attribute__((ext_vector_type(4)));

__device__ inline ushort_t f2bf(float f) {   // round-to-nearest-even
    uint_t u = __float_as_uint(f);
    return (ushort_t)((u + 0x7FFF + ((u >> 16) & 1)) >> 16);
}
__device__ inline float bf2f(ushort_t b) {
    return __uint_as_float(((uint_t)b) << 16);
}

// init strided cursors to their segment bases
__global__ __launch_bounds__(1024) void k_binit(int* __restrict__ bcur, int nbuk) {
    int t = threadIdx.x;
    if (t < nbuk) bcur[t * CSTR] = t * CAP;
}

// Pass 1: block-aggregated bucket append (R10).
__global__ __launch_bounds__(256) void k_p1(const int* __restrict__ src,
                                            const int* __restrict__ dst,
                                            const float* __restrict__ ew,
                                            int* __restrict__ bcur,
                                            int2* __restrict__ tmp, int E, int nbuk) {
    __shared__ int lcnt[NBUK_MAX];
    __shared__ int lbase[NBUK_MAX];
    const int t = threadIdx.x;
    const int base = blockIdx.x * CHUNK;
    for (int j = t; j < nbuk; j += 256) lcnt[j] = 0;
    __syncthreads();
    int d_r[EPB];
#pragma unroll
    for (int k = 0; k < EPB; ++k) {
        int e = base + k * 256 + t;
        int d = (e < E) ? dst[e] : -1;
        d_r[k] = d;
        if (d >= 0) atomicAdd(&lcnt[d >> BSHIFT], 1);
    }
    __syncthreads();
    for (int j = t; j < nbuk; j += 256) {
        int c = lcnt[j];
        lbase[j] = c ? atomicAdd(&bcur[j * CSTR], c) : 0;
        lcnt[j] = 0;
    }
    __syncthreads();
#pragma unroll
    for (int k = 0; k < EPB; ++k) {
        int d = d_r[k];
        if (d < 0) continue;
        int e = base + k * 256 + t;
        int b = d >> BSHIFT;
        int p = lbase[b] + atomicAdd(&lcnt[b], 1);
        if (p >= nbuk * CAP) continue;
        int2 pk;
        pk.x = src[e] | ((d & (BNODES - 1)) << 17);
        pk.y = __float_as_int(ew[e]);
        tmp[p] = pk;
    }
}

// Scan final bucket counts -> dense boff[nbuk+1].
__global__ __launch_bounds__(1024) void k_pscan(const int* __restrict__ bcur,
                                                int* __restrict__ boff, int nbuk) {
    __shared__ int lds[1024];
    const int t = threadIdx.x;
    int v = (t < nbuk) ? (bcur[t * CSTR] - t * CAP) : 0;
    lds[t] = v;
    __syncthreads();
    for (int off = 1; off < 1024; off <<= 1) {
        int u = (t >= off) ? lds[t - off] : 0;
        __syncthreads();
        lds[t] += u;
        __syncthreads();
    }
    if (t < nbuk) boff[t] = lds[t] - v;
    if (t == nbuk - 1) boff[nbuk] = lds[t];
}

// Pass 2: per-bucket finalize -> dense CSR epack {src, ew}, rowptr, dinv.
__global__ __launch_bounds__(256) void k_p2(const int2* __restrict__ tmp,
                                            const int* __restrict__ bcur,
                                            const int* __restrict__ boff,
                                            int* __restrict__ rowptr,
                                            int2* __restrict__ epack,
                                            float* __restrict__ dinv,
                                            int n, int nbuk) {
    __shared__ int cnt[BNODES];
    __shared__ int pos[BNODES];
    __shared__ float degf[BNODES];
    const int b = blockIdx.x, t = threadIdx.x;
    const int node0 = b << BSHIFT;
    if (t < BNODES) { cnt[t] = 0; degf[t] = 0.f; }
    __syncthreads();
    const int lo_t = b * CAP, hi_t = bcur[b * CSTR];
    const int outb = boff[b];
    for (int i = lo_t + t; i < hi_t; i += 256) {
        int2 pk = tmp[i];
        int dlo = (pk.x >> 17) & (BNODES - 1);
        atomicAdd(&cnt[dlo], 1);
        atomicAdd(&degf[dlo], __int_as_float(pk.y));
    }
    __syncthreads();
    int own = (t < BNODES) ? cnt[t] : 0;
    if (t < BNODES) pos[t] = own;
    __syncthreads();
    for (int off = 1; off < BNODES; off <<= 1) {
        int u = (t < BNODES && t >= off) ? pos[t - off] : 0;
        __syncthreads();
        if (t < BNODES) pos[t] += u;
        __syncthreads();
    }
    if (t < BNODES) {
        int excl = pos[t] - own;
        int node = node0 + t;
        if (node < n) {
            rowptr[node] = outb + excl;
            dinv[node] = rsqrtf(1.0f + degf[t]);
        }
        pos[t] = excl;
    }
    if (b == nbuk - 1 && t == 0) rowptr[n] = outb + (hi_t - lo_t);
    __syncthreads();
    for (int i = lo_t + t; i < hi_t; i += 256) {
        int2 pk = tmp[i];
        int dlo = (pk.x >> 17) & (BNODES - 1);
        int p = outb + atomicAdd(&pos[dlo], 1);
        int2 o;
        o.x = pk.x & 0x1FFFF;
        o.y = pk.y;
        epack[p] = o;
    }
}

// h1s[n][64] (bf16) = (x[n][128] @ W[128][64]) * dinv[node]
// 64-node block; thread = (ng, fg) owns nodes {ng+16j} x feats {4fg..4fg+3}.
// K in two 64-halves staged in xs[64][68] (pad => conflict-free b128 reads).
__global__ __launch_bounds__(256) void k_gemm1(const float* __restrict__ x,
                                               const float* __restrict__ W,
                                               const float* __restrict__ dinv,
                                               ushort_t* __restrict__ h, int n) {
    __shared__ float Ws[128 * 64];   // 32 KB  [k][f]
    __shared__ float xs[64][68];     // 17 KB  half-K tile, +4 pad
    const int t = threadIdx.x;
    for (int i = t; i < 128 * 64; i += 256) Ws[i] = W[i];
    const int node0 = blockIdx.x * 64;
    const int fg = t & 15;           // feature quad: f = 4fg..4fg+3
    const int ng = t >> 4;           // 0..15; this thread's nodes: ng + 16j
    float4 acc[4];
#pragma unroll
    for (int j = 0; j < 4; ++j) acc[j] = make_float4(0.f, 0.f, 0.f, 0.f);
    const float4* Ws4 = (const float4*)Ws;   // Ws4[k*16 + fg]
    for (int half = 0; half < 2; ++half) {
        __syncthreads();             // xs reuse guard (also orders Ws staging)
        for (int i = t; i < 64 * 16; i += 256) {
            int nn = i >> 4, q = i & 15;
            int node = node0 + nn;
            float4 v = (node < n) ? ((const float4*)x)[(size_t)node * 32 + half * 16 + q]
                                  : make_float4(0.f, 0.f, 0.f, 0.f);
            *(float4*)&xs[nn][q * 4] = v;
        }
        __syncthreads();
#pragma unroll 4
        for (int kb = 0; kb < 16; ++kb) {
            float4 xv[4];
#pragma unroll
            for (int j = 0; j < 4; ++j)
                xv[j] = *(const float4*)&xs[ng + 16 * j][kb * 4];
            const int kg = half * 64 + kb * 4;
            float4 w0 = Ws4[(kg + 0) * 16 + fg];
            float4 w1 = Ws4[(kg + 1) * 16 + fg];
            float4 w2 = Ws4[(kg + 2) * 16 + fg];
            float4 w3 = Ws4[(kg + 3) * 16 + fg];
#pragma unroll
            for (int j = 0; j < 4; ++j) {
                acc[j].x = fmaf(xv[j].x, w0.x, acc[j].x);
                acc[j].y = fmaf(xv[j].x, w0.y, acc[j].y);
                acc[j].z = fmaf(xv[j].x, w0.z, acc[j].z);
                acc[j].w = fmaf(xv[j].x, w0.w, acc[j].w);
                acc[j].x = fmaf(xv[j].y, w1.x, acc[j].x);
                acc[j].y = fmaf(xv[j].y, w1.y, acc[j].y);
                acc[j].z = fmaf(xv[j].y, w1.z, acc[j].z);
                acc[j].w = fmaf(xv[j].y, w1.w, acc[j].w);
                acc[j].x = fmaf(xv[j].z, w2.x, acc[j].x);
                acc[j].y = fmaf(xv[j].z, w2.y, acc[j].y);
                acc[j].z = fmaf(xv[j].z, w2.z, acc[j].z);
                acc[j].w = fmaf(xv[j].z, w2.w, acc[j].w);
                acc[j].x = fmaf(xv[j].w, w3.x, acc[j].x);
                acc[j].y = fmaf(xv[j].w, w3.y, acc[j].y);
                acc[j].z = fmaf(xv[j].w, w3.z, acc[j].z);
                acc[j].w = fmaf(xv[j].w, w3.w, acc[j].w);
            }
        }
    }
#pragma unroll
    for (int j = 0; j < 4; ++j) {
        int node = node0 + ng + 16 * j;
        if (node < n) {
            float di = dinv[node];
            us4 pk;
            pk.x = f2bf(acc[j].x * di);
            pk.y = f2bf(acc[j].y * di);
            pk.z = f2bf(acc[j].z * di);
            pk.w = f2bf(acc[j].w * di);
            *(us4*)(h + (size_t)node * 64 + fg * 4) = pk;   // one 8B store
        }
    }
}

// Gather-aggregate, F=64, bf16 h: one wave per node, lane = feature.
// Double-buffered ep prefetch; readfirstlane'd node for SGPR addressing.
__global__ __launch_bounds__(256) void k_agg64(const ushort_t* __restrict__ h,
                                               const int* __restrict__ rowptr,
                                               const int2* __restrict__ ep,
                                               const float* __restrict__ dinv,
                                               float* __restrict__ agg, int n) {
    const int node = __builtin_amdgcn_readfirstlane((int)((blockIdx.x * 256 + threadIdx.x) >> 6));
    const int lane = threadIdx.x & 63;
    if (node >= n) return;
    const float di = dinv[node];
    const int lo = rowptr[node], hi = rowptr[node + 1];
    const ushort_t* __restrict__ hl = h + lane;
    float accE = 0.f;
    int i = lo;
    if (i + 8 <= hi) {
        int2 pb[8], nb[8];
#pragma unroll
        for (int k = 0; k < 8; ++k) pb[k] = ep[i + k];
        i += 8;
        for (; i + 8 <= hi; i += 8) {
            // issue next batch's ep loads first (independent of pb)
#pragma unroll
            for (int k = 0; k < 8; ++k) nb[k] = ep[i + k];
            float v[8];
#pragma unroll
            for (int k = 0; k < 8; ++k) v[k] = bf2f(hl[(size_t)pb[k].x * 64]);
#pragma unroll
            for (int k = 0; k < 8; ++k) accE = fmaf(v[k], __int_as_float(pb[k].y), accE);
#pragma unroll
            for (int k = 0; k < 8; ++k) pb[k] = nb[k];
        }
        {   // drain last full batch
            float v[8];
#pragma unroll
            for (int k = 0; k < 8; ++k) v[k] = bf2f(hl[(size_t)pb[k].x * 64]);
#pragma unroll
            for (int k = 0; k < 8; ++k) accE = fmaf(v[k], __int_as_float(pb[k].y), accE);
        }
    }
    for (; i < hi; ++i) {
        int2 p = ep[i];
        accE = fmaf(bf2f(hl[(size_t)p.x * 64]), __int_as_float(p.y), accE);
    }
    float self = bf2f(hl[(size_t)node * 64]);
    agg[(size_t)node * 64 + lane] = di * (accE + self);
}

// Gather-aggregate, F=16, bf16 h: 16-lane group per node, 4 rows in flight.
__global__ __launch_bounds__(256) void k_agg16(const ushort_t* __restrict__ h,
                                               const int* __restrict__ rowptr,
                                               const int2* __restrict__ ep,
                                               const float* __restrict__ dinv,
                                               float* __restrict__ agg, int n) {
    const int node = (blockIdx.x * 256 + threadIdx.x) >> 4;
    const int lane = threadIdx.x & 15;
    if (node >= n) return;
    const float di = dinv[node];
    float accE = 0.f;
    const int lo = rowptr[node], hi = rowptr[node + 1];
    int i = lo;
    for (; i + 3 < hi; i += 4) {
        int2 p0 = ep[i], p1 = ep[i + 1], p2 = ep[i + 2], p3 = ep[i + 3];
        float v0 = bf2f(h[(size_t)p0.x * 16 + lane]);
        float v1 = bf2f(h[(size_t)p1.x * 16 + lane]);
        float v2 = bf2f(h[(size_t)p2.x * 16 + lane]);
        float v3 = bf2f(h[(size_t)p3.x * 16 + lane]);
        accE = fmaf(v0, __int_as_float(p0.y), accE);
        accE = fmaf(v1, __int_as_float(p1.y), accE);
        accE = fmaf(v2, __int_as_float(p2.y), accE);
        accE = fmaf(v3, __int_as_float(p3.y), accE);
    }
    for (; i < hi; ++i) {
        int2 p = ep[i];
        accE = fmaf(bf2f(h[(size_t)p.x * 16 + lane]), __int_as_float(p.y), accE);
    }
    float self = bf2f(h[(size_t)node * 16 + lane]);
    agg[(size_t)node * 16 + lane] = di * (accE + self);
}

// h2s[n][16] (bf16) = (relu(a[n][64] + b1) @ W[64][16]) * dinv[node]
__global__ __launch_bounds__(256) void k_gemm2(const float* __restrict__ a,
                                               const float* __restrict__ W,
                                               const float* __restrict__ b1,
                                               const float* __restrict__ dinv,
                                               ushort_t* __restrict__ h2, int n) {
    __shared__ float Ws[64 * 16];
    __shared__ float xs[32][68];
    const int t = threadIdx.x;
    for (int i = t; i < 64 * 16; i += 256) Ws[i] = W[i];
    const int node0 = blockIdx.x * 32;
    for (int i = t; i < 32 * 64; i += 256) {
        int nn = i >> 6, kk = i & 63;
        int node = node0 + nn;
        xs[nn][kk] = (node < n) ? fmaxf(a[(size_t)node * 64 + kk] + b1[kk], 0.0f) : 0.0f;
    }
    __syncthreads();
    const int f = t & 15;
    const int ng = t >> 4;
    float a0 = 0.f, a1 = 0.f;
#pragma unroll 4
    for (int k = 0; k < 64; ++k) {
        float wv = Ws[k * 16 + f];
        a0 = fmaf(xs[ng][k], wv, a0);
        a1 = fmaf(xs[ng + 16][k], wv, a1);
    }
    if (node0 + ng < n)
        h2[(size_t)(node0 + ng) * 16 + f] = f2bf(a0 * dinv[node0 + ng]);
    if (node0 + ng + 16 < n)
        h2[(size_t)(node0 + ng + 16) * 16 + f] = f2bf(a1 * dinv[node0 + ng + 16]);
}

// In-place: out[i][:] = log_softmax(out[i][:] + b2)
__global__ void k_logsoftmax(float* __restrict__ out, const float* __restrict__ b2, int n) {
    int i = blockIdx.x * blockDim.x + threadIdx.x;
    if (i >= n) return;
    const size_t base = (size_t)i * 16;
    float v[16];
#pragma unroll
    for (int f = 0; f < 16; ++f) v[f] = out[base + f] + b2[f];
    float m = v[0];
#pragma unroll
    for (int f = 1; f < 16; ++f) m = fmaxf(m, v[f]);
    float s = 0.f;
#pragma unroll
    for (int f = 0; f < 16; ++f) s += __expf(v[f] - m);
    float lse = __logf(s);
#pragma unroll
    for (int f = 0; f < 16; ++f) out[base + f] = v[f] - m - lse;
}

extern "C" void kernel_launch(void* const* d_in, const int* in_sizes, int n_in,
                              void* d_out, int out_size, void* d_ws, size_t ws_size,
                              hipStream_t stream) {
    const float* x  = (const float*)d_in[0];
    const int*   ei = (const int*)d_in[1];   // [2, E]
    const float* ew = (const float*)d_in[2];
    const float* W1 = (const float*)d_in[3];
    const float* b1 = (const float*)d_in[4];
    const float* W2 = (const float*)d_in[5];
    const float* b2 = (const float*)d_in[6];
    float* out = (float*)d_out;

    const int n = in_sizes[0] / 128;  // 100000
    const int E = in_sizes[2];        // 1600000
    const int* srcv = ei;
    const int* dstv = ei + E;
    const int nbuk = (n + BNODES - 1) >> BSHIFT;  // 782

    // Workspace (4B units). tmp (19.2MB) aliases agg1 (25.6MB, dead until
    // k_agg64 which runs after k_p2 retires tmp).
    float* wsf = (float*)d_ws;
    size_t off = 0;
    float* dinv = wsf + off; off += n;
    ushort_t* h1b = (ushort_t*)(wsf + off); off += (size_t)n * 32;  // bf16[n*64]; reused bf16[n*16]
    float* agg1 = wsf + off; off += (size_t)n * 64;
    off = (off + 1) & ~(size_t)1;                     // 8B align
    int2* epack = (int2*)(wsf + off); off += (size_t)E * 2;
    int* rowptr = (int*)(wsf + off); off += n + 1;
    int* boff_d = (int*)(wsf + off); off += NBUK_MAX + 1;
    int* bcur   = (int*)(wsf + off); off += (size_t)NBUK_MAX * CSTR;
    int2* tmp   = (int2*)agg1;                        // [nbuk*CAP]

    const int TB = 256;

    // --- CSR build: cursor init -> block-aggregated append -> scan -> finalize ---
    k_binit<<<1, 1024, 0, stream>>>(bcur, nbuk);
    k_p1<<<(E + CHUNK - 1) / CHUNK, TB, 0, stream>>>(srcv, dstv, ew, bcur, tmp, E, nbuk);
    k_pscan<<<1, 1024, 0, stream>>>(bcur, boff_d, nbuk);
    k_p2<<<nbuk, TB, 0, stream>>>(tmp, bcur, boff_d, rowptr, epack, dinv, n, nbuk);

    // --- layer 1: gemm (dinv-prescaled, bf16 out) + gather-agg ---
    k_gemm1<<<(n + 63) / 64, TB, 0, stream>>>(x, W1, dinv, h1b, n);
    k_agg64<<<(n * 64 + TB - 1) / TB, TB, 0, stream>>>(h1b, rowptr, epack, dinv, agg1, n);

    // --- layer 2: gemm (+bias1+relu, prescaled, bf16 out) + gather-agg into d_out ---
    k_gemm2<<<(n + 31) / 32, TB, 0, stream>>>(agg1, W2, b1, dinv, h1b, n);
    k_agg16<<<(n * 16 + TB - 1) / TB, TB, 0, stream>>>(h1b, rowptr, epack, dinv, out, n);

    // --- epilogue ---
    k_logsoftmax<<<(n + TB - 1) / TB, TB, 0, stream>>>(out, b2, n);
}